// Round 7
// baseline (1164.817 us; speedup 1.0000x reference)
//
#include <hip/hip_runtime.h>

#define DEV __device__ __forceinline__

typedef __bf16 bf16x8 __attribute__((ext_vector_type(8)));
typedef float f32x4 __attribute__((ext_vector_type(4)));
typedef unsigned short u16x4 __attribute__((ext_vector_type(4)));

DEV unsigned short f2bf(float f) {
    unsigned u = __builtin_bit_cast(unsigned, f);
    u += 0x7fffu + ((u >> 16) & 1u);   // round-to-nearest-even
    return (unsigned short)(u >> 16);
}

DEV float bf2f(unsigned short h) {
    unsigned u = (unsigned)h << 16;
    return __builtin_bit_cast(float, u);
}

// zero counts[N] + stats[1536]; pre-convert W1,W2 (6 mats) to bf16 [c][k];
// convert x -> xb (bf16); block 0 detects int64-vs-int32 edge_index layout.
// grid covers N*16 threads (8 elems each for the x conversion).
__global__ __launch_bounds__(256) void setup_kernel(
    const int* __restrict__ ei, int* __restrict__ flag,
    int* __restrict__ counts, float* __restrict__ stats,
    const float* __restrict__ W1, const float* __restrict__ W2,
    unsigned short* __restrict__ Wt,
    const float* __restrict__ x, unsigned short* __restrict__ xb, int N)
{
    int g = blockIdx.x * 256 + threadIdx.x;
    if (g < N) counts[g] = 0;
    if (g < 1536) stats[g] = 0.f;
    if (g < 12288) {                       // 6 mats x 16 k-groups x 128 cols
        int mat = g >> 11;
        int r = g & 2047;
        int c = r & 127;
        int kg = (r >> 7) * 8;
        const float* Wsrc = (mat < 3) ? (W1 + (size_t)mat * 16384)
                                      : (W2 + (size_t)(mat - 3) * 16384);
        unsigned short o[8];
#pragma unroll
        for (int q = 0; q < 8; ++q)
            o[q] = f2bf(Wsrc[(size_t)(kg + q) * 128 + c]);
        *(uint4*)(Wt + ((size_t)mat * 128 + c) * 128 + kg) = *(const uint4*)o;
    }
    // x -> xb bf16 (8 elems/thread); N*16 threads cover N*128 elems
    if (g < N * 16) {
        size_t base = (size_t)g * 8;
        float4 a = *(const float4*)(x + base);
        float4 b = *(const float4*)(x + base + 4);
        unsigned short o[8];
        o[0] = f2bf(a.x); o[1] = f2bf(a.y); o[2] = f2bf(a.z); o[3] = f2bf(a.w);
        o[4] = f2bf(b.x); o[5] = f2bf(b.y); o[6] = f2bf(b.z); o[7] = f2bf(b.w);
        *(uint4*)(xb + base) = *(const uint4*)o;
    }
    if (blockIdx.x == 0 && threadIdx.x < 64) {
        int t = threadIdx.x;
        int v = (t < 32) ? ei[2 * t + 1] : 0;
        unsigned long long b = __ballot(v == 0);
        if (t == 0) *flag = (b == ~0ull) ? 1 : 0;
    }
}

// ea (f32) -> eab (bf16), natural order, NT streaming. 8 elems/thread.
__global__ __launch_bounds__(256) void eaconv_kernel(
    const float* __restrict__ ea, unsigned short* __restrict__ eab, long long total8)
{
    long long g = (long long)blockIdx.x * 256 + threadIdx.x;
    if (g >= total8) return;
    size_t base = (size_t)g * 8;
    f32x4 a = __builtin_nontemporal_load((const f32x4*)(ea + base));
    f32x4 b = __builtin_nontemporal_load((const f32x4*)(ea + base + 4));
    u16x4 o0, o1;
    o0[0] = f2bf(a[0]); o0[1] = f2bf(a[1]); o0[2] = f2bf(a[2]); o0[3] = f2bf(a[3]);
    o1[0] = f2bf(b[0]); o1[1] = f2bf(b[1]); o1[2] = f2bf(b[2]); o1[3] = f2bf(b[3]);
    __builtin_nontemporal_store(o0, (u16x4*)(eab + base));
    __builtin_nontemporal_store(o1, (u16x4*)(eab + base + 4));
}

__global__ __launch_bounds__(256) void hist_kernel(
    const int* __restrict__ ei, const int* __restrict__ i64flag,
    int* __restrict__ counts, int E)
{
    int e = blockIdx.x * 256 + threadIdx.x;
    if (e >= E) return;
    int d = (*i64flag) ? ei[2 * (size_t)E + 2 * (size_t)e] : ei[(size_t)E + e];
    atomicAdd(&counts[d], 1);
}

// block-level inclusive scan; writes per-element exclusive offsets + block totals
__global__ __launch_bounds__(256) void scan1_kernel(
    const int* __restrict__ counts, int* __restrict__ offs,
    int* __restrict__ bsum, int N)
{
    __shared__ int s[256];
    int tid = threadIdx.x;
    int i = blockIdx.x * 256 + tid;
    int c = (i < N) ? counts[i] : 0;
    s[tid] = c;
    __syncthreads();
#pragma unroll
    for (int off = 1; off < 256; off <<= 1) {
        int add = (tid >= off) ? s[tid - off] : 0;
        __syncthreads();
        s[tid] += add;
        __syncthreads();
    }
    int incl = s[tid];
    if (i < N) offs[i] = incl - c;            // exclusive within block
    if (tid == 255) bsum[blockIdx.x] = incl;  // block total
}

// parallel exclusive scan of block sums (nb <= 256 for N = 50000)
__global__ __launch_bounds__(256) void scan2_kernel(int* __restrict__ bsum, int nb)
{
    __shared__ int s[256];
    int tid = threadIdx.x;
    int v = (tid < nb) ? bsum[tid] : 0;
    s[tid] = v;
    __syncthreads();
#pragma unroll
    for (int off = 1; off < 256; off <<= 1) {
        int add = (tid >= off) ? s[tid - off] : 0;
        __syncthreads();
        s[tid] += add;
        __syncthreads();
    }
    if (tid < nb) bsum[tid] = s[tid] - v;     // exclusive
}

__global__ __launch_bounds__(256) void scan3_kernel(
    int* __restrict__ offs, const int* __restrict__ bsum,
    int* __restrict__ cursor, int N)
{
    int i = blockIdx.x * 256 + threadIdx.x;
    if (i < N) {
        int o = offs[i] + bsum[blockIdx.x];
        offs[i] = o;
        cursor[i] = o;
    }
}

// CSR scatter: el[slot] = (src, edge_id)
__global__ __launch_bounds__(256) void scatter_kernel(
    const int* __restrict__ ei, const int* __restrict__ i64flag,
    int* __restrict__ cursor, int2* __restrict__ el, int E)
{
    int e = blockIdx.x * 256 + threadIdx.x;
    if (e >= E) return;
    int s, d;
    if (*i64flag) {
        s = ei[2 * (size_t)e];
        d = ei[2 * (size_t)E + 2 * (size_t)e];
    } else {
        s = ei[e];
        d = ei[(size_t)E + e];
    }
    int pos = atomicAdd(&cursor[d], 1);
    el[pos] = make_int2(s, e);
}

// xb = bf16(relu(BN(t3)))  -- prepares next layer's agg input; 8 elems/thread
__global__ __launch_bounds__(256) void xbn_kernel(
    const float* __restrict__ t3, const float* __restrict__ sum, const float* __restrict__ sq,
    const float* __restrict__ gamma, const float* __restrict__ beta,
    unsigned short* __restrict__ xb, int N)
{
    __shared__ float sc[128], sh[128];
    int tid = threadIdx.x;
    if (tid < 128) {
        float inv = 1.f / (float)N;
        float m = sum[tid] * inv;
        float v = sq[tid] * inv - m * m;
        v = fmaxf(v, 0.f);
        float rs = rsqrtf(v + 1e-5f);
        float gr = gamma[tid] * rs;
        sc[tid] = gr;
        sh[tid] = beta[tid] - m * gr;
    }
    __syncthreads();
    int g = blockIdx.x * 256 + tid;
    if (g >= N * 16) return;
    size_t base = (size_t)g * 8;
    int c0 = (g & 15) * 8;
    float4 a = *(const float4*)(t3 + base);
    float4 b = *(const float4*)(t3 + base + 4);
    unsigned short o[8];
    o[0] = f2bf(fmaxf(fmaf(a.x, sc[c0 + 0], sh[c0 + 0]), 0.f));
    o[1] = f2bf(fmaxf(fmaf(a.y, sc[c0 + 1], sh[c0 + 1]), 0.f));
    o[2] = f2bf(fmaxf(fmaf(a.z, sc[c0 + 2], sh[c0 + 2]), 0.f));
    o[3] = f2bf(fmaxf(fmaf(a.w, sc[c0 + 3], sh[c0 + 3]), 0.f));
    o[4] = f2bf(fmaxf(fmaf(b.x, sc[c0 + 4], sh[c0 + 4]), 0.f));
    o[5] = f2bf(fmaxf(fmaf(b.y, sc[c0 + 5], sh[c0 + 5]), 0.f));
    o[6] = f2bf(fmaxf(fmaf(b.z, sc[c0 + 6], sh[c0 + 6]), 0.f));
    o[7] = f2bf(fmaxf(fmaf(b.w, sc[c0 + 7], sh[c0 + 7]), 0.f));
    *(uint4*)(xb + base) = *(const uint4*)o;
}

// ---------------- aggregation ----------------
// t1[n] (bf16) = xb[n] + sum_{slot in CSR[n]} relu(xb[el[slot].x] + eab[el[slot].y])
// xb/eab are bf16 rows (256 B): half the gather bytes of f32.
// One wave per node; half-wave 0 takes the first ceil(deg/2) CSR slots, half 1
// the rest. 4-edge unroll keeps 8 gathers in flight per half-wave.
__global__ __launch_bounds__(512) void agg_kernel(
    const unsigned short* __restrict__ xb, const unsigned short* __restrict__ eab,
    const int2* __restrict__ el, const int* __restrict__ offs,
    const int* __restrict__ cnts,
    unsigned short* __restrict__ t1, int N)
{
    int tid = threadIdx.x;
    const int lane = tid & 63;
    const int half = lane >> 5;
    const int l32  = lane & 31;
    const int d0   = l32 * 4;

    const int n = blockIdx.x * 8 + (tid >> 6);
    if (n >= N) return;

    const int start = offs[n];
    const int deg = cnts[n];
    const int mid = (deg + 1) >> 1;
    int j        = half ? mid : 0;
    const int hi = half ? deg : mid;

    f32x4 acc = {0.f, 0.f, 0.f, 0.f};
    if (half == 0) {
        u16x4 cv = *(const u16x4*)(xb + (size_t)n * 128 + d0);
        acc[0] = bf2f(cv[0]); acc[1] = bf2f(cv[1]);
        acc[2] = bf2f(cv[2]); acc[3] = bf2f(cv[3]);
    }

#define APPLY(GX, AV) { \
    acc[0] += fmaxf(bf2f((GX)[0]) + bf2f((AV)[0]), 0.f); \
    acc[1] += fmaxf(bf2f((GX)[1]) + bf2f((AV)[1]), 0.f); \
    acc[2] += fmaxf(bf2f((GX)[2]) + bf2f((AV)[2]), 0.f); \
    acc[3] += fmaxf(bf2f((GX)[3]) + bf2f((AV)[3]), 0.f); }

    for (; j + 3 < hi; j += 4) {
        int2 e0 = el[start + j + 0];
        int2 e1 = el[start + j + 1];
        int2 e2 = el[start + j + 2];
        int2 e3 = el[start + j + 3];
        u16x4 x0 = *(const u16x4*)(xb + (size_t)e0.x * 128 + d0);
        u16x4 x1 = *(const u16x4*)(xb + (size_t)e1.x * 128 + d0);
        u16x4 x2 = *(const u16x4*)(xb + (size_t)e2.x * 128 + d0);
        u16x4 x3 = *(const u16x4*)(xb + (size_t)e3.x * 128 + d0);
        u16x4 a0 = __builtin_nontemporal_load((const u16x4*)(eab + (size_t)e0.y * 128 + d0));
        u16x4 a1 = __builtin_nontemporal_load((const u16x4*)(eab + (size_t)e1.y * 128 + d0));
        u16x4 a2 = __builtin_nontemporal_load((const u16x4*)(eab + (size_t)e2.y * 128 + d0));
        u16x4 a3 = __builtin_nontemporal_load((const u16x4*)(eab + (size_t)e3.y * 128 + d0));
        APPLY(x0, a0); APPLY(x1, a1); APPLY(x2, a2); APPLY(x3, a3);
    }
    for (; j < hi; ++j) {
        int2 e0 = el[start + j];
        u16x4 x0 = *(const u16x4*)(xb + (size_t)e0.x * 128 + d0);
        u16x4 a0 = __builtin_nontemporal_load((const u16x4*)(eab + (size_t)e0.y * 128 + d0));
        APPLY(x0, a0);
    }
#undef APPLY

    // combine the two half-wave partial sums
#pragma unroll
    for (int q = 0; q < 4; ++q) acc[q] += __shfl_xor(acc[q], 32);

    if (half == 0) {
        u16x4 o;
        o[0] = f2bf(acc[0]); o[1] = f2bf(acc[1]);
        o[2] = f2bf(acc[2]); o[3] = f2bf(acc[3]);
        *(u16x4*)(t1 + (size_t)n * 128 + d0) = o;
    }
}

// ---------------- GEMM with fused BN-affine on A (optional) + fused col stats
// out[n][c] = sum_k a[n][k]*Wt[c][k] + bias[c].  Wt is pre-converted bf16 [c][k].
// BNA=false: inp is bf16 [N][128] (pre-rounded), copied straight to LDS.
// BNA=true:  inp is f32  [N][128]; a = relu(inp*sc+sh) rounded to bf16.
// Also accumulates column sum/sumsq of out into statsOut[0..127]/[128..255].
template<bool BNA>
__global__ __launch_bounds__(256) void gemm_kernel(
    const void* __restrict__ inp,
    const unsigned short* __restrict__ Wt,  // [128][128] bf16, [c][k]
    const float* __restrict__ bias,         // [128] f32
    const float* __restrict__ statsIn,
    const float* __restrict__ gA, const float* __restrict__ bA,
    float* __restrict__ out, float* __restrict__ statsOut, int N)
{
    __shared__ __attribute__((aligned(16))) unsigned short As[64][136];   // [r][k]
    __shared__ __attribute__((aligned(16))) unsigned short Ws[128][136];  // [c][k]
    __shared__ float u0[128], u1[128];  // BNA: sc/sh during staging; then cs/cq
    const int tid = threadIdx.x;
    const int row0 = blockIdx.x * 64;

    if (BNA) {
        if (tid < 128) {
            float inv = 1.f / (float)N;
            float m = statsIn[tid] * inv;
            float v = statsIn[128 + tid] * inv - m * m;
            v = fmaxf(v, 0.f);
            float rs = rsqrtf(v + 1e-5f);
            float gr = gA[tid] * rs;
            u0[tid] = gr;
            u1[tid] = bA[tid] - m * gr;
        }
        __syncthreads();
    }

    // stage Wt -> Ws (bf16 copy, coalesced)
#pragma unroll
    for (int it = 0; it < 8; ++it) {
        int lin = (it * 256 + tid) * 8;
        int c = lin >> 7;
        int k = lin & 127;
        *(uint4*)&Ws[c][k] = *(const uint4*)(Wt + (size_t)c * 128 + k);
    }
    // stage A tile (zero-pad tail rows)
    if (BNA) {
        const float* ip = (const float*)inp;
#pragma unroll
        for (int it = 0; it < 8; ++it) {
            int lin = (it * 256 + tid) * 4;
            int r = lin >> 7;
            int c = lin & 127;
            int row = row0 + r;
            if (row < N) {
                float4 v = *(const float4*)(ip + (size_t)row * 128 + c);
                v.x = fmaxf(fmaf(v.x, u0[c + 0], u1[c + 0]), 0.f);
                v.y = fmaxf(fmaf(v.y, u0[c + 1], u1[c + 1]), 0.f);
                v.z = fmaxf(fmaf(v.z, u0[c + 2], u1[c + 2]), 0.f);
                v.w = fmaxf(fmaf(v.w, u0[c + 3], u1[c + 3]), 0.f);
                As[r][c + 0] = f2bf(v.x); As[r][c + 1] = f2bf(v.y);
                As[r][c + 2] = f2bf(v.z); As[r][c + 3] = f2bf(v.w);
            } else {
                As[r][c + 0] = 0; As[r][c + 1] = 0; As[r][c + 2] = 0; As[r][c + 3] = 0;
            }
        }
    } else {
        const unsigned short* ip = (const unsigned short*)inp;
#pragma unroll
        for (int it = 0; it < 4; ++it) {
            int lin = (it * 256 + tid) * 8;
            int r = lin >> 7;
            int c = lin & 127;
            int row = row0 + r;
            uint4 v = {0u, 0u, 0u, 0u};
            if (row < N) v = *(const uint4*)(ip + (size_t)row * 128 + c);
            *(uint4*)&As[r][c] = v;
        }
    }
    __syncthreads();
    // repurpose u0/u1 as column sum / sumsq accumulators
    if (tid < 128) { u0[tid] = 0.f; u1[tid] = 0.f; }
    __syncthreads();

    const int wave = tid >> 6;
    const int lane = tid & 63;
    const int quad = lane >> 4;
    const int m16  = lane & 15;

    // A fragments: A[m=lane&15][k=quad*8+j], 8 contiguous bf16 -> ds_read_b128
    bf16x8 af[4];
#pragma unroll
    for (int kk = 0; kk < 4; ++kk)
        af[kk] = *reinterpret_cast<const bf16x8*>(&As[wave * 16 + m16][kk * 32 + quad * 8]);

#pragma unroll
    for (int ct = 0; ct < 8; ++ct) {
        f32x4 acc = {0.f, 0.f, 0.f, 0.f};
#pragma unroll
        for (int kk = 0; kk < 4; ++kk) {
            bf16x8 bf = *reinterpret_cast<const bf16x8*>(&Ws[ct * 16 + m16][kk * 32 + quad * 8]);
            acc = __builtin_amdgcn_mfma_f32_16x16x32_bf16(af[kk], bf, acc, 0, 0, 0);
        }
        int col = ct * 16 + m16;
        float bb = bias[col];
        float s_part = 0.f, q_part = 0.f;
#pragma unroll
        for (int r = 0; r < 4; ++r) {
            int row = row0 + wave * 16 + quad * 4 + r;  // C/D: row = quad*4+reg, col = lane&15
            if (row < N) {
                float val = acc[r] + bb;
                out[(size_t)row * 128 + col] = val;
                s_part += val;
                q_part += val * val;
            }
        }
        // reduce over the 4 quad-groups that share this column (lanes ^16, ^32)
        s_part += __shfl_xor(s_part, 16); q_part += __shfl_xor(q_part, 16);
        s_part += __shfl_xor(s_part, 32); q_part += __shfl_xor(q_part, 32);
        if (lane < 16) {
            atomicAdd(&u0[col], s_part);
            atomicAdd(&u1[col], q_part);
        }
    }
    __syncthreads();
    if (tid < 128) {
        atomicAdd(&statsOut[tid],       u0[tid]);
        atomicAdd(&statsOut[128 + tid], u1[tid]);
    }
}

// out = gamma * (t - mean) * rsqrt(var + eps) + beta  (final layer, no relu)
__global__ __launch_bounds__(256) void bn_kernel(
    const float* __restrict__ t, const float* __restrict__ sum, const float* __restrict__ sq,
    const float* __restrict__ gamma, const float* __restrict__ beta,
    float* __restrict__ out, int N, int nv4)
{
    __shared__ float sc[128], sh[128];
    int tid = threadIdx.x;
    if (tid < 128) {
        float inv = 1.f / (float)N;
        float m = sum[tid] * inv;
        float v = sq[tid] * inv - m * m;
        v = fmaxf(v, 0.f);
        float rs = rsqrtf(v + 1e-5f);
        float gr = gamma[tid] * rs;
        sc[tid] = gr;
        sh[tid] = beta[tid] - m * gr;
    }
    __syncthreads();
    int g = blockIdx.x * 256 + tid;
    if (g < nv4) {
        int c = (g & 31) * 4;
        float4 v = *(const float4*)(t + (size_t)g * 4);
        float4 o;
        o.x = v.x * sc[c + 0] + sh[c + 0];
        o.y = v.y * sc[c + 1] + sh[c + 1];
        o.z = v.z * sc[c + 2] + sh[c + 2];
        o.w = v.w * sc[c + 3] + sh[c + 3];
        *(float4*)(out + (size_t)g * 4) = o;
    }
}

extern "C" void kernel_launch(void* const* d_in, const int* in_sizes, int n_in,
                              void* d_out, int out_size, void* d_ws, size_t ws_size,
                              hipStream_t stream)
{
    const float* x  = (const float*)d_in[0];
    const int* ei   = (const int*)d_in[1];
    const float* ea = (const float*)d_in[2];
    // d_in[3] = batch (unused)
    const float* W1 = (const float*)d_in[4];
    const float* b1 = (const float*)d_in[5];
    const float* gm = (const float*)d_in[6];
    const float* bm = (const float*)d_in[7];
    const float* W2 = (const float*)d_in[8];
    const float* b2 = (const float*)d_in[9];
    const float* go = (const float*)d_in[10];
    const float* bo = (const float*)d_in[11];
    float* out = (float*)d_out;

    const int N = in_sizes[0] / 128;   // 50000
    const int E = in_sizes[2] / 128;   // 800000

    char* w = (char*)d_ws;
    float* t2   = (float*)w;            w += (size_t)N * 128 * 4;   // gemm1 out (pre-BN1)
    float* t3   = (float*)w;            w += (size_t)N * 128 * 4;   // gemm2 out (pre-BN2)
    unsigned short* t1 = (unsigned short*)w; w += (size_t)N * 128 * 2;  // agg out, bf16
    unsigned short* xb = (unsigned short*)w; w += (size_t)N * 128 * 2;  // agg in, bf16
    unsigned short* Wt = (unsigned short*)w; w += (size_t)6 * 16384 * 2; // W bf16 [c][k]
    float* stats = (float*)w;           w += 1536 * 4;              // 6 x (sum[128], sq[128])
    int* i64flag = (int*)w;             w += 16;
    int* counts  = (int*)w;             w += (size_t)N * 4;
    int* offs    = (int*)w;             w += (size_t)N * 4;
    int* cursor  = (int*)w;             w += (size_t)N * 4;
    int* bsum    = (int*)w;             w += 256 * 4;
    int2* el     = (int2*)w;            w += (size_t)E * 8;         // CSR: (src, edge)
    unsigned short* eab = (unsigned short*)w; w += (size_t)E * 128 * 2;  // ea bf16

    const int nv4 = N * 32;
    const int gElem = (nv4 + 255) / 256;
    const int gGemm = (N + 63) / 64;
    const int gEdge = (E + 255) / 256;
    const int nb    = (N + 255) / 256;
    const int gAgg  = (N + 7) / 8;
    const int gConv = (N * 16 + 255) / 256;            // x->xb, xbn
    const long long ea8 = (long long)E * 16;           // 8-elem groups in ea
    const int gEa   = (int)((ea8 + 255) / 256);

    // ---- CSR build + W/x/ea pre-convert (all layer-invariant) ----
    setup_kernel<<<gConv, 256, 0, stream>>>(ei, i64flag, counts, stats, W1, W2, Wt, x, xb, N);
    hist_kernel<<<gEdge, 256, 0, stream>>>(ei, i64flag, counts, E);
    scan1_kernel<<<nb, 256, 0, stream>>>(counts, offs, bsum, N);
    scan2_kernel<<<1, 256, 0, stream>>>(bsum, nb);
    scan3_kernel<<<nb, 256, 0, stream>>>(offs, bsum, cursor, N);
    scatter_kernel<<<gEdge, 256, 0, stream>>>(ei, i64flag, cursor, el, E);
    eaconv_kernel<<<gEa, 256, 0, stream>>>(ea, eab, ea8);

    for (int i = 0; i < 3; ++i) {
        float* sMlp = stats + (size_t)i * 512;        // gemm1 output stats
        float* sOut = stats + (size_t)i * 512 + 256;  // gemm2 output stats

        if (i > 0) {
            float* sPrev = stats + (size_t)(i - 1) * 512 + 256;
            xbn_kernel<<<gConv, 256, 0, stream>>>(
                t3, sPrev, sPrev + 128, go + (i - 1) * 128, bo + (i - 1) * 128, xb, N);
        }
        agg_kernel<<<gAgg, 512, 0, stream>>>(xb, eab, el, offs, counts, t1, N);
        gemm_kernel<false><<<gGemm, 256, 0, stream>>>(
            t1, Wt + (size_t)i * 16384, b1 + i * 128,
            nullptr, nullptr, nullptr, t2, sMlp, N);
        gemm_kernel<true><<<gGemm, 256, 0, stream>>>(
            t2, Wt + (size_t)(i + 3) * 16384, b2 + i * 128,
            sMlp, gm + i * 128, bm + i * 128, t3, sOut, N);
    }
    // final outer BN (no relu) -> out
    bn_kernel<<<gElem, 256, 0, stream>>>(t3, stats + 2 * 512 + 256, stats + 2 * 512 + 384,
                                         go + 256, bo + 256, out, N, nv4);
}